// Round 4
// baseline (164.290 us; speedup 1.0000x reference)
//
#include <hip/hip_runtime.h>

#define T_DIM 32
#define N_DIM 512
#define E_DIM 64
#define F_DIM 64
#define HD    64
#define NBR_CAP 128   // max degree capacity (Binom(512,0.05) max ~55)

static_assert(E_DIM == 64 && HD == 64 && F_DIM == 64, "wave-mapped dims");

__device__ __forceinline__ float wave_sum(float v) {
    #pragma unroll
    for (int off = 32; off > 0; off >>= 1) v += __shfl_xor(v, off, 64);
    return v;
}
__device__ __forceinline__ void wave_sum2(float& a, float& b) {
    #pragma unroll
    for (int off = 32; off > 0; off >>= 1) {
        a += __shfl_xor(a, off, 64);
        b += __shfl_xor(b, off, 64);
    }
}

// ---------------------------------------------------------------------------
// K1: blocks [0,1024): h = x @ W, s_hyp/s_ind = leaky_relu(h @ a, 0.2).
//     blocks [1024,1152): CSR build from adj (ballot compaction).
//     block 1152: transpose Hm -> Ht[e][n] for coalesced edge-stats reads.
// ---------------------------------------------------------------------------
#define K1_R 16
#define K1_ROWBLK (T_DIM * N_DIM / K1_R)      // 1024
#define K1_CSRBLK (N_DIM / 4)                 // 128
__global__ __launch_bounds__(256) void k1_h_s(
    const float* __restrict__ x, const float* __restrict__ W,
    const float* __restrict__ a_hyp, const float* __restrict__ a_ind,
    const int* __restrict__ adj, const int* __restrict__ Hm,
    float* __restrict__ h, float* __restrict__ s_hyp, float* __restrict__ s_ind,
    int* __restrict__ degs, int* __restrict__ nbrs, int* __restrict__ Ht)
{
    const int wave = threadIdx.x >> 6;
    const int lane = threadIdx.x & 63;

    if (blockIdx.x < K1_ROWBLK) {
        __shared__ float xl[K1_R * F_DIM];
        const int row0 = blockIdx.x * K1_R;
        ((float4*)xl)[threadIdx.x] =
            ((const float4*)(x + (size_t)row0 * F_DIM))[threadIdx.x];
        float wcol[F_DIM];                            // W[:, lane]
        #pragma unroll
        for (int f = 0; f < F_DIM; ++f) wcol[f] = W[f * HD + lane];
        const float ah = a_hyp[lane], ai = a_ind[lane];
        __syncthreads();
        #pragma unroll
        for (int r = wave; r < K1_R; r += 4) {
            float a0 = 0.f, a1 = 0.f, a2 = 0.f, a3 = 0.f;
            #pragma unroll
            for (int f = 0; f < F_DIM; f += 4) {
                const float4 xv = *(const float4*)&xl[r * F_DIM + f];
                a0 = fmaf(xv.x, wcol[f + 0], a0);
                a1 = fmaf(xv.y, wcol[f + 1], a1);
                a2 = fmaf(xv.z, wcol[f + 2], a2);
                a3 = fmaf(xv.w, wcol[f + 3], a3);
            }
            const float acc = (a0 + a1) + (a2 + a3);
            h[(size_t)(row0 + r) * HD + lane] = acc;
            float sh = acc * ah, si = acc * ai;
            wave_sum2(sh, si);
            if (lane == 0) {
                s_hyp[row0 + r] = sh > 0.f ? sh : 0.2f * sh;
                s_ind[row0 + r] = si > 0.f ? si : 0.2f * si;
            }
        }
    } else if (blockIdx.x < K1_ROWBLK + K1_CSRBLK) {
        // CSR build: one wave per node i
        const int i = (blockIdx.x - K1_ROWBLK) * 4 + wave;
        int deg = 0;
        #pragma unroll
        for (int c = 0; c < N_DIM / 64; ++c) {
            const int j = c * 64 + lane;
            const bool bit = adj[(size_t)i * N_DIM + j] != 0;
            const unsigned long long mask = __ballot(bit);
            if (bit) {
                const int pos = deg + __popcll(mask & ((1ull << lane) - 1ull));
                nbrs[i * NBR_CAP + pos] = j;
            }
            deg += __popcll(mask);
        }
        if (lane == 0) degs[i] = deg;
    } else {
        // transpose Hm[n][e] -> Ht[e][n]
        for (int idx = threadIdx.x; idx < N_DIM * E_DIM; idx += 256) {
            const int n = idx >> 6, e = idx & 63;
            Ht[e * N_DIM + n] = Hm[idx];
        }
    }
}

// ---------------------------------------------------------------------------
// K23: blocks [0,512): per-(t,e) d_e = sum over member nodes of exp(s_hyp).
//      rest: per-(t,i) industry row via CSR (no max-subtraction).
// ---------------------------------------------------------------------------
#define K2_BLOCKS (T_DIM * E_DIM / 4)         // 512
__global__ __launch_bounds__(256) void k23_stats_industry(
    const int* __restrict__ Ht, const int* __restrict__ degs,
    const int* __restrict__ nbrs,
    const float* __restrict__ s_hyp, const float* __restrict__ s_ind,
    const float* __restrict__ h,
    float* __restrict__ d_e, float* __restrict__ industry)
{
    const int wave = threadIdx.x >> 6;
    const int lane = threadIdx.x & 63;

    if (blockIdx.x < K2_BLOCKS) {
        const int idx = blockIdx.x * 4 + wave;        // t*E + e
        const int t = idx >> 6, e = idx & 63;
        const int*   hrow = Ht + e * N_DIM;           // coalesced
        const float* srow = s_hyp + t * N_DIM;
        float sum = 0.f;
        #pragma unroll
        for (int c = 0; c < N_DIM / 64; ++c) {
            const int n = c * 64 + lane;
            if (hrow[n]) sum += expf(srow[n]);
        }
        sum = wave_sum(sum);
        if (lane == 0) d_e[idx] = sum;
    } else {
        const int idx = (blockIdx.x - K2_BLOCKS) * 4 + wave;  // t*N + i
        const int t = idx >> 9, i = idx & (N_DIM - 1);
        const int deg = degs[i];
        const int* nb = nbrs + i * NBR_CAP;
        const float* st = s_ind + t * N_DIM;
        const float* hbase = h + (size_t)t * N_DIM * HD;
        float evp = 0.f, ac0 = 0.f, ac1 = 0.f, ac2 = 0.f, ac3 = 0.f;
        for (int base = 0; base < deg; base += 64) {
            const int k = base + lane;
            const bool valid = k < deg;
            const int j = valid ? nb[k] : 0;
            const float ev = valid ? expf(st[j]) : 0.f;
            evp += ev;
            const int cnt = min(deg - base, 64);
            int kk = 0;
            for (; kk + 4 <= cnt; kk += 4) {
                const int j0 = __shfl(j, kk, 64),     j1 = __shfl(j, kk + 1, 64);
                const int j2 = __shfl(j, kk + 2, 64), j3 = __shfl(j, kk + 3, 64);
                const float w0 = __shfl(ev, kk, 64),     w1 = __shfl(ev, kk + 1, 64);
                const float w2 = __shfl(ev, kk + 2, 64), w3 = __shfl(ev, kk + 3, 64);
                const float v0 = hbase[(size_t)j0 * HD + lane];
                const float v1 = hbase[(size_t)j1 * HD + lane];
                const float v2 = hbase[(size_t)j2 * HD + lane];
                const float v3 = hbase[(size_t)j3 * HD + lane];
                ac0 = fmaf(w0, v0, ac0);
                ac1 = fmaf(w1, v1, ac1);
                ac2 = fmaf(w2, v2, ac2);
                ac3 = fmaf(w3, v3, ac3);
            }
            for (; kk < cnt; ++kk) {
                const int jj = __shfl(j, kk, 64);
                const float ww = __shfl(ev, kk, 64);
                ac0 = fmaf(ww, hbase[(size_t)jj * HD + lane], ac0);
            }
        }
        const float evsum = wave_sum(evp);
        industry[(size_t)idx * HD + lane] = ((ac0 + ac1) + (ac2 + ac3)) / evsum;
    }
}

// ---------------------------------------------------------------------------
// K4: per (t,n): y8 = edgeconv over member hyperedges (2 edges/iter, max-free
// softmax), y9 = pair edgeconv. Wc1[:,lane] in VGPRs; feats staged in LDS.
// ---------------------------------------------------------------------------
__global__ __launch_bounds__(256) void k4_final(
    const int* __restrict__ Hm, const float* __restrict__ s_hyp,
    const float* __restrict__ d_e,
    const float* __restrict__ h, const float* __restrict__ industry,
    const float* __restrict__ Wc1, const float* __restrict__ bc1,
    const float* __restrict__ wc2, const float* __restrict__ bc2,
    float* __restrict__ out)
{
    __shared__ float fl[4 * 2 * HD];
    const int wave = threadIdx.x >> 6;
    const int lane = threadIdx.x & 63;
    const int idx  = blockIdx.x * 4 + wave;           // t*N + n
    const int t = idx >> 9, n = idx & (N_DIM - 1);
    float* fw = fl + wave * 2 * HD;

    float wreg[HD];                                   // Wc1[:, lane]
    #pragma unroll
    for (int d = 0; d < HD; ++d) wreg[d] = Wc1[d * HD + lane];
    const float bc1v = bc1[lane];
    const float wc2v = wc2[lane];
    const float bc2v = bc2[0];

    const float hv = h[(size_t)idx * HD + lane];
    const float esh = expf(s_hyp[idx]);               // wave-uniform

    const int memv = Hm[n * E_DIM + lane];            // lane = e
    const float alpha = memv ? esh * __frcp_rn(d_e[t * E_DIM + lane]) : 0.f;
    unsigned long long mk = __ballot(memv != 0);

    float zsum = 0.f, acc = 0.f;
    while (mk) {
        const int e0 = __ffsll((long long)mk) - 1; mk &= mk - 1;
        const bool have1 = mk != 0;
        const int e1 = have1 ? __ffsll((long long)mk) - 1 : e0;
        if (have1) mk &= mk - 1;
        const float a0 = __shfl(alpha, e0, 64);
        const float a1 = __shfl(alpha, e1, 64);
        float f0 = a0 * hv; f0 = f0 > 0.f ? f0 : expm1f(f0);   // elu
        float f1 = a1 * hv; f1 = f1 > 0.f ? f1 : expm1f(f1);
        fw[lane]      = f0;
        fw[HD + lane] = f1;
        float u0 = 0.f, u1 = 0.f, u2 = 0.f, u3 = 0.f;
        float v0 = 0.f, v1 = 0.f, v2 = 0.f, v3 = 0.f;
        #pragma unroll
        for (int d = 0; d < HD; d += 4) {
            const float4 A = *(const float4*)&fw[d];       // broadcast b128
            const float4 B = *(const float4*)&fw[HD + d];
            u0 = fmaf(A.x, wreg[d + 0], u0);
            u1 = fmaf(A.y, wreg[d + 1], u1);
            u2 = fmaf(A.z, wreg[d + 2], u2);
            u3 = fmaf(A.w, wreg[d + 3], u3);
            v0 = fmaf(B.x, wreg[d + 0], v0);
            v1 = fmaf(B.y, wreg[d + 1], v1);
            v2 = fmaf(B.z, wreg[d + 2], v2);
            v3 = fmaf(B.w, wreg[d + 3], v3);
        }
        float p = fmaxf((u0 + u1) + (u2 + u3) + bc1v, 0.f) * wc2v;
        float q = fmaxf((v0 + v1) + (v2 + v3) + bc1v, 0.f) * wc2v;
        wave_sum2(p, q);
        const float w0 = expf(p + bc2v);
        const float w1 = have1 ? expf(q + bc2v) : 0.f;
        zsum += w0 + w1;
        acc = fmaf(w0, f0, acc);
        acc = fmaf(w1, f1, acc);
    }
    const float y8 = acc / zsum;

    // final pair edgeconv over {industry, y8} (max-free)
    const float indv = industry[(size_t)idx * HD + lane];
    fw[lane]      = indv;
    fw[HD + lane] = y8;
    float p0 = 0.f, p1 = 0.f, q0 = 0.f, q1 = 0.f;
    #pragma unroll
    for (int d = 0; d < HD; d += 4) {
        const float4 iv = *(const float4*)&fw[d];
        const float4 yv = *(const float4*)&fw[HD + d];
        p0 = fmaf(iv.x, wreg[d + 0], p0);
        p1 = fmaf(iv.y, wreg[d + 1], p1);
        p0 = fmaf(iv.z, wreg[d + 2], p0);
        p1 = fmaf(iv.w, wreg[d + 3], p1);
        q0 = fmaf(yv.x, wreg[d + 0], q0);
        q1 = fmaf(yv.y, wreg[d + 1], q1);
        q0 = fmaf(yv.z, wreg[d + 2], q0);
        q1 = fmaf(yv.w, wreg[d + 3], q1);
    }
    float zp = fmaxf(p0 + p1 + bc1v, 0.f) * wc2v;
    float zq = fmaxf(q0 + q1 + bc1v, 0.f) * wc2v;
    wave_sum2(zp, zq);
    const float w0 = expf(zp + bc2v), w1 = expf(zq + bc2v);
    out[(size_t)idx * HD + lane] = fmaf(w0, indv, w1 * y8) / (w0 + w1);
}

extern "C" void kernel_launch(void* const* d_in, const int* in_sizes, int n_in,
                              void* d_out, int out_size, void* d_ws, size_t ws_size,
                              hipStream_t stream) {
    const float* x     = (const float*)d_in[0];
    const int*   Hm    = (const int*)  d_in[1];
    const int*   adj   = (const int*)  d_in[2];
    // d_in[3] = nhid (unused scalar)
    const float* W     = (const float*)d_in[4];
    const float* a_hyp = (const float*)d_in[5];
    const float* a_ind = (const float*)d_in[6];
    const float* Wc1   = (const float*)d_in[7];
    const float* bc1   = (const float*)d_in[8];
    const float* wc2   = (const float*)d_in[9];
    const float* bc2   = (const float*)d_in[10];
    float* out = (float*)d_out;

    float* ws       = (float*)d_ws;
    float* h        = ws;                                 // T*N*HD
    float* s_hyp    = h + (size_t)T_DIM * N_DIM * HD;     // T*N
    float* s_ind    = s_hyp + T_DIM * N_DIM;              // T*N
    float* d_e      = s_ind + T_DIM * N_DIM;              // T*E
    float* industry = d_e + T_DIM * E_DIM;                // T*N*HD
    int*   degs     = (int*)(industry + (size_t)T_DIM * N_DIM * HD);  // N
    int*   nbrs     = degs + N_DIM;                       // N*NBR_CAP
    int*   Ht       = nbrs + N_DIM * NBR_CAP;             // E*N

    k1_h_s<<<K1_ROWBLK + K1_CSRBLK + 1, 256, 0, stream>>>(
        x, W, a_hyp, a_ind, adj, Hm, h, s_hyp, s_ind, degs, nbrs, Ht);
    k23_stats_industry<<<K2_BLOCKS + T_DIM * N_DIM / 4, 256, 0, stream>>>(
        Ht, degs, nbrs, s_hyp, s_ind, h, d_e, industry);
    k4_final<<<T_DIM * N_DIM / 4, 256, 0, stream>>>(
        Hm, s_hyp, d_e, h, industry, Wc1, bc1, wc2, bc2, out);
}

// Round 7
// 161.621 us; speedup vs baseline: 1.0165x; 1.0165x over previous
//
#include <hip/hip_runtime.h>

#define T_DIM 32
#define N_DIM 512
#define E_DIM 64
#define F_DIM 64
#define HD    64
#define NBR_CAP 128   // max degree capacity (Binom(512,0.05) max ~55)

static_assert(E_DIM == 64 && HD == 64 && F_DIM == 64, "wave-mapped dims");

__device__ __forceinline__ float wave_sum(float v) {
    #pragma unroll
    for (int off = 32; off > 0; off >>= 1) v += __shfl_xor(v, off, 64);
    return v;
}
__device__ __forceinline__ void wave_sum2(float& a, float& b) {
    #pragma unroll
    for (int off = 32; off > 0; off >>= 1) {
        a += __shfl_xor(a, off, 64);
        b += __shfl_xor(b, off, 64);
    }
}

// ---------------------------------------------------------------------------
// K1: blocks [0, K1_ROWBLK): h = x @ W, s_hyp/s_ind = leaky_relu(h @ a, 0.2).
//     blocks [K1_ROWBLK, +K1_CSRBLK): CSR build from adj (ballot compaction).
// ---------------------------------------------------------------------------
#define K1_R 64
#define K1_ROWBLK (T_DIM * N_DIM / K1_R)      // 256
#define K1_CSRBLK (N_DIM / 4)                 // 128
__global__ __launch_bounds__(256) void k1_h_s(
    const float* __restrict__ x, const float* __restrict__ W,
    const float* __restrict__ a_hyp, const float* __restrict__ a_ind,
    const int* __restrict__ adj,
    float* __restrict__ h, float* __restrict__ s_hyp, float* __restrict__ s_ind,
    int* __restrict__ degs, int* __restrict__ nbrs)
{
    const int wave = threadIdx.x >> 6;
    const int lane = threadIdx.x & 63;

    if (blockIdx.x < K1_ROWBLK) {
        __shared__ float xl[K1_R * F_DIM];            // 16 KB
        const int row0 = blockIdx.x * K1_R;
        #pragma unroll
        for (int c = 0; c < K1_R * F_DIM / 4 / 256; ++c)
            ((float4*)xl)[c * 256 + threadIdx.x] =
                ((const float4*)(x + (size_t)row0 * F_DIM))[c * 256 + threadIdx.x];
        float wcol[F_DIM];                            // W[:, lane]
        #pragma unroll
        for (int f = 0; f < F_DIM; ++f) wcol[f] = W[f * HD + lane];
        const float ah = a_hyp[lane], ai = a_ind[lane];
        __syncthreads();
        #pragma unroll
        for (int r = wave; r < K1_R; r += 4) {
            float a0 = 0.f, a1 = 0.f, a2 = 0.f, a3 = 0.f;
            #pragma unroll
            for (int f = 0; f < F_DIM; f += 4) {
                const float4 xv = *(const float4*)&xl[r * F_DIM + f];  // broadcast
                a0 = fmaf(xv.x, wcol[f + 0], a0);
                a1 = fmaf(xv.y, wcol[f + 1], a1);
                a2 = fmaf(xv.z, wcol[f + 2], a2);
                a3 = fmaf(xv.w, wcol[f + 3], a3);
            }
            const float acc = (a0 + a1) + (a2 + a3);
            h[(size_t)(row0 + r) * HD + lane] = acc;
            float sh = acc * ah, si = acc * ai;
            wave_sum2(sh, si);
            if (lane == 0) {
                s_hyp[row0 + r] = sh > 0.f ? sh : 0.2f * sh;
                s_ind[row0 + r] = si > 0.f ? si : 0.2f * si;
            }
        }
    } else {
        // CSR build: one wave per node i
        const int i = (blockIdx.x - K1_ROWBLK) * 4 + wave;
        int deg = 0;
        #pragma unroll
        for (int c = 0; c < N_DIM / 64; ++c) {
            const int j = c * 64 + lane;
            const bool bit = adj[(size_t)i * N_DIM + j] != 0;
            const unsigned long long mask = __ballot(bit);
            if (bit) {
                const int pos = deg + __popcll(mask & ((1ull << lane) - 1ull));
                nbrs[i * NBR_CAP + pos] = j;
            }
            deg += __popcll(mask);
        }
        if (lane == 0) degs[i] = deg;
    }
}

// ---------------------------------------------------------------------------
// K23: blocks [0, T_DIM): per-t d_e[t,e] = sum_n Hm[n,e]*exp(s_hyp[t,n])
//      (coalesced Hm ROW reads, lane = e, exps staged in LDS — no transpose).
//      rest: per-(t,i) industry row via CSR (max-free softmax).
// ---------------------------------------------------------------------------
__global__ __launch_bounds__(256) void k23_stats_industry(
    const int* __restrict__ Hm, const int* __restrict__ degs,
    const int* __restrict__ nbrs,
    const float* __restrict__ s_hyp, const float* __restrict__ s_ind,
    const float* __restrict__ h,
    float* __restrict__ d_e, float* __restrict__ industry)
{
    const int wave = threadIdx.x >> 6;
    const int lane = threadIdx.x & 63;

    if (blockIdx.x < T_DIM) {
        const int t = blockIdx.x;
        __shared__ float exps[N_DIM];
        __shared__ float departial[4][E_DIM];
        #pragma unroll
        for (int c = 0; c < N_DIM / 256; ++c)
            exps[c * 256 + threadIdx.x] = expf(s_hyp[t * N_DIM + c * 256 + threadIdx.x]);
        __syncthreads();
        float de = 0.f;
        const int n0 = wave * (N_DIM / 4);
        #pragma unroll 4
        for (int k = 0; k < N_DIM / 4; ++k) {
            const int n = n0 + k;
            const int m = Hm[n * E_DIM + lane];       // coalesced 256B row
            de += m ? exps[n] : 0.f;                  // exps[n]: LDS broadcast
        }
        departial[wave][lane] = de;
        __syncthreads();
        if (wave == 0)
            d_e[t * E_DIM + lane] = (departial[0][lane] + departial[1][lane])
                                  + (departial[2][lane] + departial[3][lane]);
    } else {
        const int idx = (blockIdx.x - T_DIM) * 4 + wave;      // t*N + i
        const int t = idx >> 9, i = idx & (N_DIM - 1);
        const int deg = degs[i];
        const int* nb = nbrs + i * NBR_CAP;
        const float* st = s_ind + t * N_DIM;
        const float* hbase = h + (size_t)t * N_DIM * HD;
        float evp = 0.f, ac0 = 0.f, ac1 = 0.f, ac2 = 0.f, ac3 = 0.f;
        for (int base = 0; base < deg; base += 64) {
            const int k = base + lane;
            const bool valid = k < deg;
            const int j = valid ? nb[k] : 0;
            const float ev = valid ? expf(st[j]) : 0.f;
            evp += ev;
            const int cnt = min(deg - base, 64);
            int kk = 0;
            for (; kk + 4 <= cnt; kk += 4) {
                const int j0 = __shfl(j, kk, 64),     j1 = __shfl(j, kk + 1, 64);
                const int j2 = __shfl(j, kk + 2, 64), j3 = __shfl(j, kk + 3, 64);
                const float w0 = __shfl(ev, kk, 64),     w1 = __shfl(ev, kk + 1, 64);
                const float w2 = __shfl(ev, kk + 2, 64), w3 = __shfl(ev, kk + 3, 64);
                const float v0 = hbase[(size_t)j0 * HD + lane];
                const float v1 = hbase[(size_t)j1 * HD + lane];
                const float v2 = hbase[(size_t)j2 * HD + lane];
                const float v3 = hbase[(size_t)j3 * HD + lane];
                ac0 = fmaf(w0, v0, ac0);
                ac1 = fmaf(w1, v1, ac1);
                ac2 = fmaf(w2, v2, ac2);
                ac3 = fmaf(w3, v3, ac3);
            }
            for (; kk < cnt; ++kk) {
                const int jj = __shfl(j, kk, 64);
                const float ww = __shfl(ev, kk, 64);
                ac0 = fmaf(ww, hbase[(size_t)jj * HD + lane], ac0);
            }
        }
        const float evsum = wave_sum(evp);
        industry[(size_t)idx * HD + lane] = ((ac0 + ac1) + (ac2 + ac3)) / evsum;
    }
}

// ---------------------------------------------------------------------------
// K4: per (t,n): y8 = edgeconv over member hyperedges (2 edges/iter, max-free
// softmax), y9 = pair edgeconv. Wc1[:,lane] in VGPRs; feats staged in LDS.
// ---------------------------------------------------------------------------
__global__ __launch_bounds__(256) void k4_final(
    const int* __restrict__ Hm, const float* __restrict__ s_hyp,
    const float* __restrict__ d_e,
    const float* __restrict__ h, const float* __restrict__ industry,
    const float* __restrict__ Wc1, const float* __restrict__ bc1,
    const float* __restrict__ wc2, const float* __restrict__ bc2,
    float* __restrict__ out)
{
    __shared__ float fl[4 * 2 * HD];
    const int wave = threadIdx.x >> 6;
    const int lane = threadIdx.x & 63;
    const int idx  = blockIdx.x * 4 + wave;           // t*N + n
    const int t = idx >> 9, n = idx & (N_DIM - 1);
    float* fw = fl + wave * 2 * HD;

    float wreg[HD];                                   // Wc1[:, lane]
    #pragma unroll
    for (int d = 0; d < HD; ++d) wreg[d] = Wc1[d * HD + lane];
    const float bc1v = bc1[lane];
    const float wc2v = wc2[lane];
    const float bc2v = bc2[0];

    const float hv = h[(size_t)idx * HD + lane];
    const float esh = expf(s_hyp[idx]);               // wave-uniform

    const int memv = Hm[n * E_DIM + lane];            // lane = e
    const float alpha = memv ? esh * __frcp_rn(d_e[t * E_DIM + lane]) : 0.f;
    unsigned long long mk = __ballot(memv != 0);

    float zsum = 0.f, acc = 0.f;
    while (mk) {
        const int e0 = __ffsll((long long)mk) - 1; mk &= mk - 1;
        const bool have1 = mk != 0;
        const int e1 = have1 ? __ffsll((long long)mk) - 1 : e0;
        if (have1) mk &= mk - 1;
        const float a0 = __shfl(alpha, e0, 64);
        const float a1 = __shfl(alpha, e1, 64);
        float f0 = a0 * hv; f0 = f0 > 0.f ? f0 : expm1f(f0);   // elu
        float f1 = a1 * hv; f1 = f1 > 0.f ? f1 : expm1f(f1);
        fw[lane]      = f0;
        fw[HD + lane] = f1;
        float u0 = 0.f, u1 = 0.f, u2 = 0.f, u3 = 0.f;
        float v0 = 0.f, v1 = 0.f, v2 = 0.f, v3 = 0.f;
        #pragma unroll
        for (int d = 0; d < HD; d += 4) {
            const float4 A = *(const float4*)&fw[d];       // broadcast b128
            const float4 B = *(const float4*)&fw[HD + d];
            u0 = fmaf(A.x, wreg[d + 0], u0);
            u1 = fmaf(A.y, wreg[d + 1], u1);
            u2 = fmaf(A.z, wreg[d + 2], u2);
            u3 = fmaf(A.w, wreg[d + 3], u3);
            v0 = fmaf(B.x, wreg[d + 0], v0);
            v1 = fmaf(B.y, wreg[d + 1], v1);
            v2 = fmaf(B.z, wreg[d + 2], v2);
            v3 = fmaf(B.w, wreg[d + 3], v3);
        }
        float p = fmaxf((u0 + u1) + (u2 + u3) + bc1v, 0.f) * wc2v;
        float q = fmaxf((v0 + v1) + (v2 + v3) + bc1v, 0.f) * wc2v;
        wave_sum2(p, q);
        const float w0 = expf(p + bc2v);
        const float w1 = have1 ? expf(q + bc2v) : 0.f;
        zsum += w0 + w1;
        acc = fmaf(w0, f0, acc);
        acc = fmaf(w1, f1, acc);
    }
    const float y8 = acc / zsum;

    // final pair edgeconv over {industry, y8} (max-free)
    const float indv = industry[(size_t)idx * HD + lane];
    fw[lane]      = indv;
    fw[HD + lane] = y8;
    float p0 = 0.f, p1 = 0.f, q0 = 0.f, q1 = 0.f;
    #pragma unroll
    for (int d = 0; d < HD; d += 4) {
        const float4 iv = *(const float4*)&fw[d];
        const float4 yv = *(const float4*)&fw[HD + d];
        p0 = fmaf(iv.x, wreg[d + 0], p0);
        p1 = fmaf(iv.y, wreg[d + 1], p1);
        p0 = fmaf(iv.z, wreg[d + 2], p0);
        p1 = fmaf(iv.w, wreg[d + 3], p1);
        q0 = fmaf(yv.x, wreg[d + 0], q0);
        q1 = fmaf(yv.y, wreg[d + 1], q1);
        q0 = fmaf(yv.z, wreg[d + 2], q0);
        q1 = fmaf(yv.w, wreg[d + 3], q1);
    }
    float zp = fmaxf(p0 + p1 + bc1v, 0.f) * wc2v;
    float zq = fmaxf(q0 + q1 + bc1v, 0.f) * wc2v;
    wave_sum2(zp, zq);
    const float w0 = expf(zp + bc2v), w1 = expf(zq + bc2v);
    out[(size_t)idx * HD + lane] = fmaf(w0, indv, w1 * y8) / (w0 + w1);
}

extern "C" void kernel_launch(void* const* d_in, const int* in_sizes, int n_in,
                              void* d_out, int out_size, void* d_ws, size_t ws_size,
                              hipStream_t stream) {
    const float* x     = (const float*)d_in[0];
    const int*   Hm    = (const int*)  d_in[1];
    const int*   adj   = (const int*)  d_in[2];
    // d_in[3] = nhid (unused scalar)
    const float* W     = (const float*)d_in[4];
    const float* a_hyp = (const float*)d_in[5];
    const float* a_ind = (const float*)d_in[6];
    const float* Wc1   = (const float*)d_in[7];
    const float* bc1   = (const float*)d_in[8];
    const float* wc2   = (const float*)d_in[9];
    const float* bc2   = (const float*)d_in[10];
    float* out = (float*)d_out;

    float* ws       = (float*)d_ws;
    float* h        = ws;                                 // T*N*HD
    float* s_hyp    = h + (size_t)T_DIM * N_DIM * HD;     // T*N
    float* s_ind    = s_hyp + T_DIM * N_DIM;              // T*N
    float* d_e      = s_ind + T_DIM * N_DIM;              // T*E
    float* industry = d_e + T_DIM * E_DIM;                // T*N*HD
    int*   degs     = (int*)(industry + (size_t)T_DIM * N_DIM * HD);  // N
    int*   nbrs     = degs + N_DIM;                       // N*NBR_CAP

    k1_h_s<<<K1_ROWBLK + K1_CSRBLK, 256, 0, stream>>>(
        x, W, a_hyp, a_ind, adj, h, s_hyp, s_ind, degs, nbrs);
    k23_stats_industry<<<T_DIM + T_DIM * N_DIM / 4, 256, 0, stream>>>(
        Hm, degs, nbrs, s_hyp, s_ind, h, d_e, industry);
    k4_final<<<T_DIM * N_DIM / 4, 256, 0, stream>>>(
        Hm, s_hyp, d_e, h, industry, Wc1, bc1, wc2, bc2, out);
}

// Round 8
// 156.028 us; speedup vs baseline: 1.0530x; 1.0358x over previous
//
#include <hip/hip_runtime.h>

#define T_DIM 32
#define N_DIM 512
#define E_DIM 64
#define F_DIM 64
#define HD    64
#define NBR_CAP 128   // max degree capacity (Binom(512,0.05) max ~55)

static_assert(E_DIM == 64 && HD == 64 && F_DIM == 64, "wave-mapped dims");

__device__ __forceinline__ float wave_sum(float v) {
    #pragma unroll
    for (int off = 32; off > 0; off >>= 1) v += __shfl_xor(v, off, 64);
    return v;
}
__device__ __forceinline__ void wave_sum2(float& a, float& b) {
    #pragma unroll
    for (int off = 32; off > 0; off >>= 1) {
        a += __shfl_xor(a, off, 64);
        b += __shfl_xor(b, off, 64);
    }
}

// ---------------------------------------------------------------------------
// K1: blocks [0, K1_ROWBLK): h = x @ W, s_hyp/s_ind = leaky_relu(h @ a, 0.2).
//     blocks [K1_ROWBLK, +K1_CSRBLK): CSR build from adj (ballot compaction).
// K1_R = 16: measured-good in R2/R3 (1024 row-blocks, 4 rows/wave).
// ---------------------------------------------------------------------------
#define K1_R 16
#define K1_ROWBLK (T_DIM * N_DIM / K1_R)      // 1024
#define K1_CSRBLK (N_DIM / 4)                 // 128
__global__ __launch_bounds__(256) void k1_h_s(
    const float* __restrict__ x, const float* __restrict__ W,
    const float* __restrict__ a_hyp, const float* __restrict__ a_ind,
    const int* __restrict__ adj,
    float* __restrict__ h, float* __restrict__ s_hyp, float* __restrict__ s_ind,
    int* __restrict__ degs, int* __restrict__ nbrs)
{
    const int wave = threadIdx.x >> 6;
    const int lane = threadIdx.x & 63;

    if (blockIdx.x < K1_ROWBLK) {
        __shared__ float xl[K1_R * F_DIM];            // 4 KB
        const int row0 = blockIdx.x * K1_R;
        ((float4*)xl)[threadIdx.x] =
            ((const float4*)(x + (size_t)row0 * F_DIM))[threadIdx.x];
        float wcol[F_DIM];                            // W[:, lane]
        #pragma unroll
        for (int f = 0; f < F_DIM; ++f) wcol[f] = W[f * HD + lane];
        const float ah = a_hyp[lane], ai = a_ind[lane];
        __syncthreads();
        #pragma unroll
        for (int r = wave; r < K1_R; r += 4) {
            float a0 = 0.f, a1 = 0.f, a2 = 0.f, a3 = 0.f;
            #pragma unroll
            for (int f = 0; f < F_DIM; f += 4) {
                const float4 xv = *(const float4*)&xl[r * F_DIM + f];  // broadcast
                a0 = fmaf(xv.x, wcol[f + 0], a0);
                a1 = fmaf(xv.y, wcol[f + 1], a1);
                a2 = fmaf(xv.z, wcol[f + 2], a2);
                a3 = fmaf(xv.w, wcol[f + 3], a3);
            }
            const float acc = (a0 + a1) + (a2 + a3);
            h[(size_t)(row0 + r) * HD + lane] = acc;
            float sh = acc * ah, si = acc * ai;
            wave_sum2(sh, si);
            if (lane == 0) {
                s_hyp[row0 + r] = sh > 0.f ? sh : 0.2f * sh;
                s_ind[row0 + r] = si > 0.f ? si : 0.2f * si;
            }
        }
    } else {
        // CSR build: one wave per node i
        const int i = (blockIdx.x - K1_ROWBLK) * 4 + wave;
        int deg = 0;
        #pragma unroll
        for (int c = 0; c < N_DIM / 64; ++c) {
            const int j = c * 64 + lane;
            const bool bit = adj[(size_t)i * N_DIM + j] != 0;
            const unsigned long long mask = __ballot(bit);
            if (bit) {
                const int pos = deg + __popcll(mask & ((1ull << lane) - 1ull));
                nbrs[i * NBR_CAP + pos] = j;
            }
            deg += __popcll(mask);
        }
        if (lane == 0) degs[i] = deg;
    }
}

// ---------------------------------------------------------------------------
// K23: blocks [0, T_DIM): per-t d_e[t,e] = sum_n Hm[n,e]*exp(s_hyp[t,n])
//      (coalesced Hm ROW reads, lane = e, exps staged in LDS).
//      rest: per-(t,i) industry row via CSR; (j, ev) staged in per-wave LDS,
//      gather runs 8 independent row-loads per round, zero shfl/ballot in loop.
// ---------------------------------------------------------------------------
__global__ __launch_bounds__(256) void k23_stats_industry(
    const int* __restrict__ Hm, const int* __restrict__ degs,
    const int* __restrict__ nbrs,
    const float* __restrict__ s_hyp, const float* __restrict__ s_ind,
    const float* __restrict__ h,
    float* __restrict__ d_e, float* __restrict__ industry)
{
    const int wave = threadIdx.x >> 6;
    const int lane = threadIdx.x & 63;

    if (blockIdx.x < T_DIM) {
        const int t = blockIdx.x;
        __shared__ float exps[N_DIM];
        __shared__ float departial[4][E_DIM];
        #pragma unroll
        for (int c = 0; c < N_DIM / 256; ++c)
            exps[c * 256 + threadIdx.x] = expf(s_hyp[t * N_DIM + c * 256 + threadIdx.x]);
        __syncthreads();
        float de = 0.f;
        const int n0 = wave * (N_DIM / 4);
        #pragma unroll 4
        for (int k = 0; k < N_DIM / 4; ++k) {
            const int n = n0 + k;
            const int m = Hm[n * E_DIM + lane];       // coalesced 256B row
            de += m ? exps[n] : 0.f;                  // exps[n]: LDS broadcast
        }
        departial[wave][lane] = de;
        __syncthreads();
        if (wave == 0)
            d_e[t * E_DIM + lane] = (departial[0][lane] + departial[1][lane])
                                  + (departial[2][lane] + departial[3][lane]);
    } else {
        __shared__ int   jl[4][64];
        __shared__ float el[4][64];
        const int idx = (blockIdx.x - T_DIM) * 4 + wave;      // t*N + i
        const int t = idx >> 9, i = idx & (N_DIM - 1);
        const int deg = degs[i];
        const int* nb = nbrs + i * NBR_CAP;
        const float* st = s_ind + t * N_DIM;
        const float* hbase = h + (size_t)t * N_DIM * HD;
        float evp = 0.f, ac0 = 0.f, ac1 = 0.f, ac2 = 0.f, ac3 = 0.f;
        for (int base = 0; base < deg; base += 64) {
            const int k = base + lane;
            const bool valid = k < deg;
            const int j = valid ? nb[k] : 0;
            const float ev = valid ? expf(st[j]) : 0.f;   // ev=0 pads the tail
            evp += ev;
            jl[wave][lane] = j;                 // wave-private: no barrier needed
            el[wave][lane] = ev;
            const int cnt = min(deg - base, 64);
            const int cnt8 = (cnt + 7) & ~7;    // round up; pads contribute 0
            for (int kk = 0; kk < cnt8; kk += 8) {
                const int   j0 = jl[wave][kk + 0], j1 = jl[wave][kk + 1];
                const int   j2 = jl[wave][kk + 2], j3 = jl[wave][kk + 3];
                const int   j4 = jl[wave][kk + 4], j5 = jl[wave][kk + 5];
                const int   j6 = jl[wave][kk + 6], j7 = jl[wave][kk + 7];
                const float w0 = el[wave][kk + 0], w1 = el[wave][kk + 1];
                const float w2 = el[wave][kk + 2], w3 = el[wave][kk + 3];
                const float w4 = el[wave][kk + 4], w5 = el[wave][kk + 5];
                const float w6 = el[wave][kk + 6], w7 = el[wave][kk + 7];
                const float v0 = hbase[(size_t)j0 * HD + lane];
                const float v1 = hbase[(size_t)j1 * HD + lane];
                const float v2 = hbase[(size_t)j2 * HD + lane];
                const float v3 = hbase[(size_t)j3 * HD + lane];
                const float v4 = hbase[(size_t)j4 * HD + lane];
                const float v5 = hbase[(size_t)j5 * HD + lane];
                const float v6 = hbase[(size_t)j6 * HD + lane];
                const float v7 = hbase[(size_t)j7 * HD + lane];
                ac0 = fmaf(w0, v0, ac0);
                ac1 = fmaf(w1, v1, ac1);
                ac2 = fmaf(w2, v2, ac2);
                ac3 = fmaf(w3, v3, ac3);
                ac0 = fmaf(w4, v4, ac0);
                ac1 = fmaf(w5, v5, ac1);
                ac2 = fmaf(w6, v6, ac2);
                ac3 = fmaf(w7, v7, ac3);
            }
        }
        const float evsum = wave_sum(evp);
        industry[(size_t)idx * HD + lane] = ((ac0 + ac1) + (ac2 + ac3)) / evsum;
    }
}

// ---------------------------------------------------------------------------
// K4: per (t,n): y8 = edgeconv over member hyperedges (2 edges/iter, max-free
// softmax), y9 = pair edgeconv. Wc1[:,lane] in VGPRs; feats staged in LDS.
// ---------------------------------------------------------------------------
__global__ __launch_bounds__(256) void k4_final(
    const int* __restrict__ Hm, const float* __restrict__ s_hyp,
    const float* __restrict__ d_e,
    const float* __restrict__ h, const float* __restrict__ industry,
    const float* __restrict__ Wc1, const float* __restrict__ bc1,
    const float* __restrict__ wc2, const float* __restrict__ bc2,
    float* __restrict__ out)
{
    __shared__ float fl[4 * 2 * HD];
    const int wave = threadIdx.x >> 6;
    const int lane = threadIdx.x & 63;
    const int idx  = blockIdx.x * 4 + wave;           // t*N + n
    const int t = idx >> 9, n = idx & (N_DIM - 1);
    float* fw = fl + wave * 2 * HD;

    float wreg[HD];                                   // Wc1[:, lane]
    #pragma unroll
    for (int d = 0; d < HD; ++d) wreg[d] = Wc1[d * HD + lane];
    const float bc1v = bc1[lane];
    const float wc2v = wc2[lane];
    const float bc2v = bc2[0];

    const float hv = h[(size_t)idx * HD + lane];
    const float esh = expf(s_hyp[idx]);               // wave-uniform

    const int memv = Hm[n * E_DIM + lane];            // lane = e
    const float alpha = memv ? esh * __frcp_rn(d_e[t * E_DIM + lane]) : 0.f;
    unsigned long long mk = __ballot(memv != 0);

    float zsum = 0.f, acc = 0.f;
    while (mk) {
        const int e0 = __ffsll((long long)mk) - 1; mk &= mk - 1;
        const bool have1 = mk != 0;
        const int e1 = have1 ? __ffsll((long long)mk) - 1 : e0;
        if (have1) mk &= mk - 1;
        const float a0 = __shfl(alpha, e0, 64);
        const float a1 = __shfl(alpha, e1, 64);
        float f0 = a0 * hv; f0 = f0 > 0.f ? f0 : expm1f(f0);   // elu
        float f1 = a1 * hv; f1 = f1 > 0.f ? f1 : expm1f(f1);
        fw[lane]      = f0;
        fw[HD + lane] = f1;
        float u0 = 0.f, u1 = 0.f, u2 = 0.f, u3 = 0.f;
        float v0 = 0.f, v1 = 0.f, v2 = 0.f, v3 = 0.f;
        #pragma unroll
        for (int d = 0; d < HD; d += 4) {
            const float4 A = *(const float4*)&fw[d];       // broadcast b128
            const float4 B = *(const float4*)&fw[HD + d];
            u0 = fmaf(A.x, wreg[d + 0], u0);
            u1 = fmaf(A.y, wreg[d + 1], u1);
            u2 = fmaf(A.z, wreg[d + 2], u2);
            u3 = fmaf(A.w, wreg[d + 3], u3);
            v0 = fmaf(B.x, wreg[d + 0], v0);
            v1 = fmaf(B.y, wreg[d + 1], v1);
            v2 = fmaf(B.z, wreg[d + 2], v2);
            v3 = fmaf(B.w, wreg[d + 3], v3);
        }
        float p = fmaxf((u0 + u1) + (u2 + u3) + bc1v, 0.f) * wc2v;
        float q = fmaxf((v0 + v1) + (v2 + v3) + bc1v, 0.f) * wc2v;
        wave_sum2(p, q);
        const float w0 = expf(p + bc2v);
        const float w1 = have1 ? expf(q + bc2v) : 0.f;
        zsum += w0 + w1;
        acc = fmaf(w0, f0, acc);
        acc = fmaf(w1, f1, acc);
    }
    const float y8 = acc / zsum;

    // final pair edgeconv over {industry, y8} (max-free)
    const float indv = industry[(size_t)idx * HD + lane];
    fw[lane]      = indv;
    fw[HD + lane] = y8;
    float p0 = 0.f, p1 = 0.f, q0 = 0.f, q1 = 0.f;
    #pragma unroll
    for (int d = 0; d < HD; d += 4) {
        const float4 iv = *(const float4*)&fw[d];
        const float4 yv = *(const float4*)&fw[HD + d];
        p0 = fmaf(iv.x, wreg[d + 0], p0);
        p1 = fmaf(iv.y, wreg[d + 1], p1);
        p0 = fmaf(iv.z, wreg[d + 2], p0);
        p1 = fmaf(iv.w, wreg[d + 3], p1);
        q0 = fmaf(yv.x, wreg[d + 0], q0);
        q1 = fmaf(yv.y, wreg[d + 1], q1);
        q0 = fmaf(yv.z, wreg[d + 2], q0);
        q1 = fmaf(yv.w, wreg[d + 3], q1);
    }
    float zp = fmaxf(p0 + p1 + bc1v, 0.f) * wc2v;
    float zq = fmaxf(q0 + q1 + bc1v, 0.f) * wc2v;
    wave_sum2(zp, zq);
    const float w0 = expf(zp + bc2v), w1 = expf(zq + bc2v);
    out[(size_t)idx * HD + lane] = fmaf(w0, indv, w1 * y8) / (w0 + w1);
}

extern "C" void kernel_launch(void* const* d_in, const int* in_sizes, int n_in,
                              void* d_out, int out_size, void* d_ws, size_t ws_size,
                              hipStream_t stream) {
    const float* x     = (const float*)d_in[0];
    const int*   Hm    = (const int*)  d_in[1];
    const int*   adj   = (const int*)  d_in[2];
    // d_in[3] = nhid (unused scalar)
    const float* W     = (const float*)d_in[4];
    const float* a_hyp = (const float*)d_in[5];
    const float* a_ind = (const float*)d_in[6];
    const float* Wc1   = (const float*)d_in[7];
    const float* bc1   = (const float*)d_in[8];
    const float* wc2   = (const float*)d_in[9];
    const float* bc2   = (const float*)d_in[10];
    float* out = (float*)d_out;

    float* ws       = (float*)d_ws;
    float* h        = ws;                                 // T*N*HD
    float* s_hyp    = h + (size_t)T_DIM * N_DIM * HD;     // T*N
    float* s_ind    = s_hyp + T_DIM * N_DIM;              // T*N
    float* d_e      = s_ind + T_DIM * N_DIM;              // T*E
    float* industry = d_e + T_DIM * E_DIM;                // T*N*HD
    int*   degs     = (int*)(industry + (size_t)T_DIM * N_DIM * HD);  // N
    int*   nbrs     = degs + N_DIM;                       // N*NBR_CAP

    k1_h_s<<<K1_ROWBLK + K1_CSRBLK, 256, 0, stream>>>(
        x, W, a_hyp, a_ind, adj, h, s_hyp, s_ind, degs, nbrs);
    k23_stats_industry<<<T_DIM + T_DIM * N_DIM / 4, 256, 0, stream>>>(
        Hm, degs, nbrs, s_hyp, s_ind, h, d_e, industry);
    k4_final<<<T_DIM * N_DIM / 4, 256, 0, stream>>>(
        Hm, s_hyp, d_e, h, industry, Wc1, bc1, wc2, bc2, out);
}

// Round 9
// 155.102 us; speedup vs baseline: 1.0592x; 1.0060x over previous
//
#include <hip/hip_runtime.h>

#define T_DIM 32
#define N_DIM 512
#define E_DIM 64
#define F_DIM 64
#define HD    64
#define NBR_CAP 128   // max degree capacity (Binom(512,0.05) max ~55)

static_assert(E_DIM == 64 && HD == 64 && F_DIM == 64, "wave-mapped dims");

__device__ __forceinline__ float wave_sum(float v) {
    #pragma unroll
    for (int off = 32; off > 0; off >>= 1) v += __shfl_xor(v, off, 64);
    return v;
}
__device__ __forceinline__ void wave_sum2(float& a, float& b) {
    #pragma unroll
    for (int off = 32; off > 0; off >>= 1) {
        a += __shfl_xor(a, off, 64);
        b += __shfl_xor(b, off, 64);
    }
}

// ---------------------------------------------------------------------------
// K1: blocks [0, K1_ROWBLK): h = x @ W, s_hyp/s_ind = leaky_relu(h @ a, 0.2).
//     blocks [K1_ROWBLK, +K1_CSRBLK): CSR build from adj (ballot compaction).
// ---------------------------------------------------------------------------
#define K1_R 16
#define K1_ROWBLK (T_DIM * N_DIM / K1_R)      // 1024
#define K1_CSRBLK (N_DIM / 4)                 // 128
__global__ __launch_bounds__(256) void k1_h_s(
    const float* __restrict__ x, const float* __restrict__ W,
    const float* __restrict__ a_hyp, const float* __restrict__ a_ind,
    const int* __restrict__ adj,
    float* __restrict__ h, float* __restrict__ s_hyp, float* __restrict__ s_ind,
    int* __restrict__ degs, int* __restrict__ nbrs)
{
    const int wave = threadIdx.x >> 6;
    const int lane = threadIdx.x & 63;

    if (blockIdx.x < K1_ROWBLK) {
        __shared__ float xl[K1_R * F_DIM];            // 4 KB
        const int row0 = blockIdx.x * K1_R;
        ((float4*)xl)[threadIdx.x] =
            ((const float4*)(x + (size_t)row0 * F_DIM))[threadIdx.x];
        float wcol[F_DIM];                            // W[:, lane]
        #pragma unroll
        for (int f = 0; f < F_DIM; ++f) wcol[f] = W[f * HD + lane];
        const float ah = a_hyp[lane], ai = a_ind[lane];
        __syncthreads();
        #pragma unroll
        for (int r = wave; r < K1_R; r += 4) {
            float a0 = 0.f, a1 = 0.f, a2 = 0.f, a3 = 0.f;
            #pragma unroll
            for (int f = 0; f < F_DIM; f += 4) {
                const float4 xv = *(const float4*)&xl[r * F_DIM + f];  // broadcast
                a0 = fmaf(xv.x, wcol[f + 0], a0);
                a1 = fmaf(xv.y, wcol[f + 1], a1);
                a2 = fmaf(xv.z, wcol[f + 2], a2);
                a3 = fmaf(xv.w, wcol[f + 3], a3);
            }
            const float acc = (a0 + a1) + (a2 + a3);
            h[(size_t)(row0 + r) * HD + lane] = acc;
            float sh = acc * ah, si = acc * ai;
            wave_sum2(sh, si);
            if (lane == 0) {
                s_hyp[row0 + r] = sh > 0.f ? sh : 0.2f * sh;
                s_ind[row0 + r] = si > 0.f ? si : 0.2f * si;
            }
        }
    } else {
        // CSR build: one wave per node i
        const int i = (blockIdx.x - K1_ROWBLK) * 4 + wave;
        int deg = 0;
        #pragma unroll
        for (int c = 0; c < N_DIM / 64; ++c) {
            const int j = c * 64 + lane;
            const bool bit = adj[(size_t)i * N_DIM + j] != 0;
            const unsigned long long mask = __ballot(bit);
            if (bit) {
                const int pos = deg + __popcll(mask & ((1ull << lane) - 1ull));
                nbrs[i * NBR_CAP + pos] = j;
            }
            deg += __popcll(mask);
        }
        if (lane == 0) degs[i] = deg;
    }
}

// ---------------------------------------------------------------------------
// K23: blocks [0, T_DIM): per-t d_e[t,e] = sum_n Hm[n,e]*exp(s_hyp[t,n]).
//      rest: per-(t,i) industry row via CSR.
//      XCD-aware remap: xcd B&7 owns t in {4*xcd..4*xcd+3} -> h slices stay
//      L2-hot per XCD. float4 gather: 4 neighbor rows per load instruction.
// ---------------------------------------------------------------------------
__global__ __launch_bounds__(256) void k23_stats_industry(
    const int* __restrict__ Hm, const int* __restrict__ degs,
    const int* __restrict__ nbrs,
    const float* __restrict__ s_hyp, const float* __restrict__ s_ind,
    const float* __restrict__ h,
    float* __restrict__ d_e, float* __restrict__ industry)
{
    const int wave = threadIdx.x >> 6;
    const int lane = threadIdx.x & 63;

    if (blockIdx.x < T_DIM) {
        const int t = blockIdx.x;
        __shared__ float exps[N_DIM];
        __shared__ float departial[4][E_DIM];
        #pragma unroll
        for (int c = 0; c < N_DIM / 256; ++c)
            exps[c * 256 + threadIdx.x] = expf(s_hyp[t * N_DIM + c * 256 + threadIdx.x]);
        __syncthreads();
        float de = 0.f;
        const int n0 = wave * (N_DIM / 4);
        #pragma unroll 4
        for (int k = 0; k < N_DIM / 4; ++k) {
            const int n = n0 + k;
            const int m = Hm[n * E_DIM + lane];       // coalesced 256B row
            de += m ? exps[n] : 0.f;                  // exps[n]: LDS broadcast
        }
        departial[wave][lane] = de;
        __syncthreads();
        if (wave == 0)
            d_e[t * E_DIM + lane] = (departial[0][lane] + departial[1][lane])
                                  + (departial[2][lane] + departial[3][lane]);
    } else {
        __shared__ int   jl[4][64];
        __shared__ float el[4][64];
        const int B   = blockIdx.x - T_DIM;           // [0, 4096); B%8 == hw XCD
        const int xcd = B & 7;
        const int pos = B >> 3;                       // [0, 512)
        const int t   = xcd * 4 + (pos >> 7);         // 4 t-slices per XCD
        const int i   = ((pos & 127) << 2) + wave;
        const int idx = (t << 9) + i;
        const int grp = lane >> 4, sub = lane & 15;

        const int deg = degs[i];
        const int* nb = nbrs + i * NBR_CAP;
        const float* st = s_ind + t * N_DIM;
        const float* hbase = h + (size_t)t * N_DIM * HD;

        float evp = 0.f;
        float4 acc = {0.f, 0.f, 0.f, 0.f};
        for (int base = 0; base < deg; base += 64) {
            const int k = base + lane;
            const bool valid = k < deg;
            const int j = valid ? nb[k] : 0;
            const float ev = valid ? expf(st[j]) : 0.f;   // ev=0 pads all slots
            evp += ev;
            jl[wave][lane] = j;                 // wave-private, no barrier
            el[wave][lane] = ev;
            const int cnt = min(deg - base, 64);
            for (int kk = 0; kk < cnt; kk += 16) {
                // 16 neighbors per unrolled round; lane group grp picks one of 4
                const int   j0 = jl[wave][kk + grp];
                const int   j1 = jl[wave][kk + 4 + grp];
                const int   j2 = jl[wave][kk + 8 + grp];
                const int   j3 = jl[wave][kk + 12 + grp];
                const float w0 = el[wave][kk + grp];
                const float w1 = el[wave][kk + 4 + grp];
                const float w2 = el[wave][kk + 8 + grp];
                const float w3 = el[wave][kk + 12 + grp];
                const float4 v0 = *(const float4*)&hbase[(size_t)j0 * HD + sub * 4];
                const float4 v1 = *(const float4*)&hbase[(size_t)j1 * HD + sub * 4];
                const float4 v2 = *(const float4*)&hbase[(size_t)j2 * HD + sub * 4];
                const float4 v3 = *(const float4*)&hbase[(size_t)j3 * HD + sub * 4];
                acc.x = fmaf(w0, v0.x, acc.x);
                acc.y = fmaf(w0, v0.y, acc.y);
                acc.z = fmaf(w0, v0.z, acc.z);
                acc.w = fmaf(w0, v0.w, acc.w);
                acc.x = fmaf(w1, v1.x, acc.x);
                acc.y = fmaf(w1, v1.y, acc.y);
                acc.z = fmaf(w1, v1.z, acc.z);
                acc.w = fmaf(w1, v1.w, acc.w);
                acc.x = fmaf(w2, v2.x, acc.x);
                acc.y = fmaf(w2, v2.y, acc.y);
                acc.z = fmaf(w2, v2.z, acc.z);
                acc.w = fmaf(w2, v2.w, acc.w);
                acc.x = fmaf(w3, v3.x, acc.x);
                acc.y = fmaf(w3, v3.y, acc.y);
                acc.z = fmaf(w3, v3.z, acc.z);
                acc.w = fmaf(w3, v3.w, acc.w);
            }
        }
        // reduce across the 4 lane-groups (grp axis = lane bits 4,5)
        #pragma unroll
        for (int off = 16; off <= 32; off <<= 1) {
            acc.x += __shfl_xor(acc.x, off, 64);
            acc.y += __shfl_xor(acc.y, off, 64);
            acc.z += __shfl_xor(acc.z, off, 64);
            acc.w += __shfl_xor(acc.w, off, 64);
        }
        const float evsum = wave_sum(evp);
        if (grp == 0) {                               // lanes 0..15: 256B store
            const float r = __frcp_rn(evsum);
            float4 o;
            o.x = acc.x * r; o.y = acc.y * r; o.z = acc.z * r; o.w = acc.w * r;
            *(float4*)&industry[(size_t)idx * HD + sub * 4] = o;
        }
    }
}

// ---------------------------------------------------------------------------
// K4: per (t,n): y8 = edgeconv over member hyperedges (2 edges/iter, max-free
// softmax), y9 = pair edgeconv. Wc1[:,lane] in VGPRs; feats staged in LDS.
// ---------------------------------------------------------------------------
__global__ __launch_bounds__(256) void k4_final(
    const int* __restrict__ Hm, const float* __restrict__ s_hyp,
    const float* __restrict__ d_e,
    const float* __restrict__ h, const float* __restrict__ industry,
    const float* __restrict__ Wc1, const float* __restrict__ bc1,
    const float* __restrict__ wc2, const float* __restrict__ bc2,
    float* __restrict__ out)
{
    __shared__ float fl[4 * 2 * HD];
    const int wave = threadIdx.x >> 6;
    const int lane = threadIdx.x & 63;
    const int idx  = blockIdx.x * 4 + wave;           // t*N + n
    const int t = idx >> 9, n = idx & (N_DIM - 1);
    float* fw = fl + wave * 2 * HD;

    float wreg[HD];                                   // Wc1[:, lane]
    #pragma unroll
    for (int d = 0; d < HD; ++d) wreg[d] = Wc1[d * HD + lane];
    const float bc1v = bc1[lane];
    const float wc2v = wc2[lane];
    const float bc2v = bc2[0];

    const float hv = h[(size_t)idx * HD + lane];
    const float esh = expf(s_hyp[idx]);               // wave-uniform

    const int memv = Hm[n * E_DIM + lane];            // lane = e
    const float alpha = memv ? esh * __frcp_rn(d_e[t * E_DIM + lane]) : 0.f;
    unsigned long long mk = __ballot(memv != 0);

    float zsum = 0.f, acc = 0.f;
    while (mk) {
        const int e0 = __ffsll((long long)mk) - 1; mk &= mk - 1;
        const bool have1 = mk != 0;
        const int e1 = have1 ? __ffsll((long long)mk) - 1 : e0;
        if (have1) mk &= mk - 1;
        const float a0 = __shfl(alpha, e0, 64);
        const float a1 = __shfl(alpha, e1, 64);
        float f0 = a0 * hv; f0 = f0 > 0.f ? f0 : expm1f(f0);   // elu
        float f1 = a1 * hv; f1 = f1 > 0.f ? f1 : expm1f(f1);
        fw[lane]      = f0;
        fw[HD + lane] = f1;
        float u0 = 0.f, u1 = 0.f, u2 = 0.f, u3 = 0.f;
        float v0 = 0.f, v1 = 0.f, v2 = 0.f, v3 = 0.f;
        #pragma unroll
        for (int d = 0; d < HD; d += 4) {
            const float4 A = *(const float4*)&fw[d];       // broadcast b128
            const float4 B = *(const float4*)&fw[HD + d];
            u0 = fmaf(A.x, wreg[d + 0], u0);
            u1 = fmaf(A.y, wreg[d + 1], u1);
            u2 = fmaf(A.z, wreg[d + 2], u2);
            u3 = fmaf(A.w, wreg[d + 3], u3);
            v0 = fmaf(B.x, wreg[d + 0], v0);
            v1 = fmaf(B.y, wreg[d + 1], v1);
            v2 = fmaf(B.z, wreg[d + 2], v2);
            v3 = fmaf(B.w, wreg[d + 3], v3);
        }
        float p = fmaxf((u0 + u1) + (u2 + u3) + bc1v, 0.f) * wc2v;
        float q = fmaxf((v0 + v1) + (v2 + v3) + bc1v, 0.f) * wc2v;
        wave_sum2(p, q);
        const float w0 = expf(p + bc2v);
        const float w1 = have1 ? expf(q + bc2v) : 0.f;
        zsum += w0 + w1;
        acc = fmaf(w0, f0, acc);
        acc = fmaf(w1, f1, acc);
    }
    const float y8 = acc / zsum;

    // final pair edgeconv over {industry, y8} (max-free)
    const float indv = industry[(size_t)idx * HD + lane];
    fw[lane]      = indv;
    fw[HD + lane] = y8;
    float p0 = 0.f, p1 = 0.f, q0 = 0.f, q1 = 0.f;
    #pragma unroll
    for (int d = 0; d < HD; d += 4) {
        const float4 iv = *(const float4*)&fw[d];
        const float4 yv = *(const float4*)&fw[HD + d];
        p0 = fmaf(iv.x, wreg[d + 0], p0);
        p1 = fmaf(iv.y, wreg[d + 1], p1);
        p0 = fmaf(iv.z, wreg[d + 2], p0);
        p1 = fmaf(iv.w, wreg[d + 3], p1);
        q0 = fmaf(yv.x, wreg[d + 0], q0);
        q1 = fmaf(yv.y, wreg[d + 1], q1);
        q0 = fmaf(yv.z, wreg[d + 2], q0);
        q1 = fmaf(yv.w, wreg[d + 3], q1);
    }
    float zp = fmaxf(p0 + p1 + bc1v, 0.f) * wc2v;
    float zq = fmaxf(q0 + q1 + bc1v, 0.f) * wc2v;
    wave_sum2(zp, zq);
    const float w0 = expf(zp + bc2v), w1 = expf(zq + bc2v);
    out[(size_t)idx * HD + lane] = fmaf(w0, indv, w1 * y8) / (w0 + w1);
}

extern "C" void kernel_launch(void* const* d_in, const int* in_sizes, int n_in,
                              void* d_out, int out_size, void* d_ws, size_t ws_size,
                              hipStream_t stream) {
    const float* x     = (const float*)d_in[0];
    const int*   Hm    = (const int*)  d_in[1];
    const int*   adj   = (const int*)  d_in[2];
    // d_in[3] = nhid (unused scalar)
    const float* W     = (const float*)d_in[4];
    const float* a_hyp = (const float*)d_in[5];
    const float* a_ind = (const float*)d_in[6];
    const float* Wc1   = (const float*)d_in[7];
    const float* bc1   = (const float*)d_in[8];
    const float* wc2   = (const float*)d_in[9];
    const float* bc2   = (const float*)d_in[10];
    float* out = (float*)d_out;

    float* ws       = (float*)d_ws;
    float* h        = ws;                                 // T*N*HD
    float* s_hyp    = h + (size_t)T_DIM * N_DIM * HD;     // T*N
    float* s_ind    = s_hyp + T_DIM * N_DIM;              // T*N
    float* d_e      = s_ind + T_DIM * N_DIM;              // T*E
    float* industry = d_e + T_DIM * E_DIM;                // T*N*HD
    int*   degs     = (int*)(industry + (size_t)T_DIM * N_DIM * HD);  // N
    int*   nbrs     = degs + N_DIM;                       // N*NBR_CAP

    k1_h_s<<<K1_ROWBLK + K1_CSRBLK, 256, 0, stream>>>(
        x, W, a_hyp, a_ind, adj, h, s_hyp, s_ind, degs, nbrs);
    k23_stats_industry<<<T_DIM + T_DIM * N_DIM / 4, 256, 0, stream>>>(
        Hm, degs, nbrs, s_hyp, s_ind, h, d_e, industry);
    k4_final<<<T_DIM * N_DIM / 4, 256, 0, stream>>>(
        Hm, s_hyp, d_e, h, industry, Wc1, bc1, wc2, bc2, out);
}

// Round 10
// 149.945 us; speedup vs baseline: 1.0957x; 1.0344x over previous
//
#include <hip/hip_runtime.h>

#define T_DIM 32
#define N_DIM 512
#define E_DIM 64
#define F_DIM 64
#define HD    64
#define NBR_CAP 128   // max degree capacity (Binom(512,0.05) max ~55)

static_assert(E_DIM == 64 && HD == 64 && F_DIM == 64, "wave-mapped dims");

__device__ __forceinline__ float wave_sum(float v) {
    #pragma unroll
    for (int off = 32; off > 0; off >>= 1) v += __shfl_xor(v, off, 64);
    return v;
}
__device__ __forceinline__ void wave_sum2(float& a, float& b) {
    #pragma unroll
    for (int off = 32; off > 0; off >>= 1) {
        a += __shfl_xor(a, off, 64);
        b += __shfl_xor(b, off, 64);
    }
}

// ---------------------------------------------------------------------------
// K1: blocks [0, K1_ROWBLK): h = x @ W, s_hyp/s_ind = leaky_relu(h @ a, 0.2).
//     blocks [K1_ROWBLK, +K1_CSRBLK): CSR build from adj (ballot compaction).
// ---------------------------------------------------------------------------
#define K1_R 16
#define K1_ROWBLK (T_DIM * N_DIM / K1_R)      // 1024
#define K1_CSRBLK (N_DIM / 4)                 // 128
__global__ __launch_bounds__(256) void k1_h_s(
    const float* __restrict__ x, const float* __restrict__ W,
    const float* __restrict__ a_hyp, const float* __restrict__ a_ind,
    const int* __restrict__ adj,
    float* __restrict__ h, float* __restrict__ s_hyp, float* __restrict__ s_ind,
    int* __restrict__ degs, int* __restrict__ nbrs)
{
    const int wave = threadIdx.x >> 6;
    const int lane = threadIdx.x & 63;

    if (blockIdx.x < K1_ROWBLK) {
        __shared__ float xl[K1_R * F_DIM];            // 4 KB
        const int row0 = blockIdx.x * K1_R;
        ((float4*)xl)[threadIdx.x] =
            ((const float4*)(x + (size_t)row0 * F_DIM))[threadIdx.x];
        float wcol[F_DIM];                            // W[:, lane]
        #pragma unroll
        for (int f = 0; f < F_DIM; ++f) wcol[f] = W[f * HD + lane];
        const float ah = a_hyp[lane], ai = a_ind[lane];
        __syncthreads();
        #pragma unroll
        for (int r = wave; r < K1_R; r += 4) {
            float a0 = 0.f, a1 = 0.f, a2 = 0.f, a3 = 0.f;
            #pragma unroll
            for (int f = 0; f < F_DIM; f += 4) {
                const float4 xv = *(const float4*)&xl[r * F_DIM + f];  // broadcast
                a0 = fmaf(xv.x, wcol[f + 0], a0);
                a1 = fmaf(xv.y, wcol[f + 1], a1);
                a2 = fmaf(xv.z, wcol[f + 2], a2);
                a3 = fmaf(xv.w, wcol[f + 3], a3);
            }
            const float acc = (a0 + a1) + (a2 + a3);
            h[(size_t)(row0 + r) * HD + lane] = acc;
            float sh = acc * ah, si = acc * ai;
            wave_sum2(sh, si);
            if (lane == 0) {
                s_hyp[row0 + r] = sh > 0.f ? sh : 0.2f * sh;
                s_ind[row0 + r] = si > 0.f ? si : 0.2f * si;
            }
        }
    } else {
        // CSR build: one wave per node i
        const int i = (blockIdx.x - K1_ROWBLK) * 4 + wave;
        int deg = 0;
        #pragma unroll
        for (int c = 0; c < N_DIM / 64; ++c) {
            const int j = c * 64 + lane;
            const bool bit = adj[(size_t)i * N_DIM + j] != 0;
            const unsigned long long mask = __ballot(bit);
            if (bit) {
                const int pos = deg + __popcll(mask & ((1ull << lane) - 1ull));
                nbrs[i * NBR_CAP + pos] = j;
            }
            deg += __popcll(mask);
        }
        if (lane == 0) degs[i] = deg;
    }
}

// ---------------------------------------------------------------------------
// K2: 32 blocks, per-t d_e[t,e] = sum_n Hm[n,e]*exp(s_hyp[t,n])
//     (coalesced Hm ROW reads, lane = e, exps staged in LDS).
// ---------------------------------------------------------------------------
__global__ __launch_bounds__(256) void k2_de(
    const int* __restrict__ Hm, const float* __restrict__ s_hyp,
    float* __restrict__ d_e)
{
    const int wave = threadIdx.x >> 6;
    const int lane = threadIdx.x & 63;
    const int t = blockIdx.x;
    __shared__ float exps[N_DIM];
    __shared__ float departial[4][E_DIM];
    #pragma unroll
    for (int c = 0; c < N_DIM / 256; ++c)
        exps[c * 256 + threadIdx.x] = expf(s_hyp[t * N_DIM + c * 256 + threadIdx.x]);
    __syncthreads();
    float de = 0.f;
    const int n0 = wave * (N_DIM / 4);
    #pragma unroll 4
    for (int k = 0; k < N_DIM / 4; ++k) {
        const int n = n0 + k;
        const int m = Hm[n * E_DIM + lane];           // coalesced 256B row
        de += m ? exps[n] : 0.f;
    }
    departial[wave][lane] = de;
    __syncthreads();
    if (wave == 0)
        d_e[t * E_DIM + lane] = (departial[0][lane] + departial[1][lane])
                              + (departial[2][lane] + departial[3][lane]);
}

// ---------------------------------------------------------------------------
// K3 fused: per (t,n) wave —
//   (1) industry row via CSR gather (float4, 16 neighbors/round, XCD remap),
//   (2) y8 = edgeconv over member hyperedges (2 edges/iter, max-free),
//   (3) y9 = pair edgeconv over {industry, y8}.
// industry never round-trips to global memory.
// ---------------------------------------------------------------------------
__global__ __launch_bounds__(256) void k3_fused(
    const int* __restrict__ Hm, const int* __restrict__ degs,
    const int* __restrict__ nbrs,
    const float* __restrict__ s_hyp, const float* __restrict__ s_ind,
    const float* __restrict__ d_e, const float* __restrict__ h,
    const float* __restrict__ Wc1, const float* __restrict__ bc1,
    const float* __restrict__ wc2, const float* __restrict__ bc2,
    float* __restrict__ out)
{
    __shared__ float fl[4 * 3 * HD];                  // 3 KB: indv / A / B slots
    __shared__ int   jl[4][64];                       // gather staging
    __shared__ float el[4][64];
    const int wave = threadIdx.x >> 6;
    const int lane = threadIdx.x & 63;
    // XCD-aware remap: xcd B&7 owns t in {4*xcd..4*xcd+3} (h slice L2-hot)
    const int B   = blockIdx.x;                       // [0, 4096)
    const int xcd = B & 7;
    const int pos = B >> 3;                           // [0, 512)
    const int t   = xcd * 4 + (pos >> 7);
    const int n   = ((pos & 127) << 2) + wave;
    const int idx = (t << 9) + n;
    const int grp = lane >> 4, sub = lane & 15;
    float* fw = fl + wave * 3 * HD;                   // slot0 indv, slot1/2 scratch

    // ---- (1) industry gather ----
    const int deg = degs[n];
    const int* nb = nbrs + n * NBR_CAP;
    const float* st = s_ind + t * N_DIM;
    const float* hbase = h + (size_t)t * N_DIM * HD;

    float evp = 0.f;
    float4 acc4 = {0.f, 0.f, 0.f, 0.f};
    for (int base = 0; base < deg; base += 64) {
        const int k = base + lane;
        const bool valid = k < deg;
        const int j = valid ? nb[k] : 0;
        const float ev = valid ? expf(st[j]) : 0.f;   // ev=0 pads all slots
        evp += ev;
        jl[wave][lane] = j;                           // wave-private, no barrier
        el[wave][lane] = ev;
        const int cnt = min(deg - base, 64);
        for (int kk = 0; kk < cnt; kk += 16) {
            const int   j0 = jl[wave][kk + grp];
            const int   j1 = jl[wave][kk + 4 + grp];
            const int   j2 = jl[wave][kk + 8 + grp];
            const int   j3 = jl[wave][kk + 12 + grp];
            const float w0 = el[wave][kk + grp];
            const float w1 = el[wave][kk + 4 + grp];
            const float w2 = el[wave][kk + 8 + grp];
            const float w3 = el[wave][kk + 12 + grp];
            const float4 v0 = *(const float4*)&hbase[(size_t)j0 * HD + sub * 4];
            const float4 v1 = *(const float4*)&hbase[(size_t)j1 * HD + sub * 4];
            const float4 v2 = *(const float4*)&hbase[(size_t)j2 * HD + sub * 4];
            const float4 v3 = *(const float4*)&hbase[(size_t)j3 * HD + sub * 4];
            acc4.x = fmaf(w0, v0.x, acc4.x); acc4.y = fmaf(w0, v0.y, acc4.y);
            acc4.z = fmaf(w0, v0.z, acc4.z); acc4.w = fmaf(w0, v0.w, acc4.w);
            acc4.x = fmaf(w1, v1.x, acc4.x); acc4.y = fmaf(w1, v1.y, acc4.y);
            acc4.z = fmaf(w1, v1.z, acc4.z); acc4.w = fmaf(w1, v1.w, acc4.w);
            acc4.x = fmaf(w2, v2.x, acc4.x); acc4.y = fmaf(w2, v2.y, acc4.y);
            acc4.z = fmaf(w2, v2.z, acc4.z); acc4.w = fmaf(w2, v2.w, acc4.w);
            acc4.x = fmaf(w3, v3.x, acc4.x); acc4.y = fmaf(w3, v3.y, acc4.y);
            acc4.z = fmaf(w3, v3.z, acc4.z); acc4.w = fmaf(w3, v3.w, acc4.w);
        }
    }
    #pragma unroll
    for (int off = 16; off <= 32; off <<= 1) {
        acc4.x += __shfl_xor(acc4.x, off, 64);
        acc4.y += __shfl_xor(acc4.y, off, 64);
        acc4.z += __shfl_xor(acc4.z, off, 64);
        acc4.w += __shfl_xor(acc4.w, off, 64);
    }
    const float evsum = wave_sum(evp);
    if (grp == 0) {                                   // stage indv into slot0
        const float r = __frcp_rn(evsum);
        float4 o;
        o.x = acc4.x * r; o.y = acc4.y * r; o.z = acc4.z * r; o.w = acc4.w * r;
        *(float4*)&fw[sub * 4] = o;
    }

    // ---- MLP weights ----
    float wreg[HD];                                   // Wc1[:, lane]
    #pragma unroll
    for (int d = 0; d < HD; ++d) wreg[d] = Wc1[d * HD + lane];
    const float bc1v = bc1[lane];
    const float wc2v = wc2[lane];
    const float bc2v = bc2[0];

    // ---- (2) y8 edgeconv over member hyperedges ----
    const float hv = h[(size_t)idx * HD + lane];
    const float esh = expf(s_hyp[idx]);               // wave-uniform
    const int memv = Hm[n * E_DIM + lane];            // lane = e
    const float alpha = memv ? esh * __frcp_rn(d_e[t * E_DIM + lane]) : 0.f;
    unsigned long long mk = __ballot(memv != 0);

    float zsum = 0.f, acc = 0.f;
    while (mk) {
        const int e0 = __ffsll((long long)mk) - 1; mk &= mk - 1;
        const bool have1 = mk != 0;
        const int e1 = have1 ? __ffsll((long long)mk) - 1 : e0;
        if (have1) mk &= mk - 1;
        const float a0 = __shfl(alpha, e0, 64);
        const float a1 = __shfl(alpha, e1, 64);
        float f0 = a0 * hv; f0 = f0 > 0.f ? f0 : expm1f(f0);   // elu
        float f1 = a1 * hv; f1 = f1 > 0.f ? f1 : expm1f(f1);
        fw[HD + lane]     = f0;
        fw[2 * HD + lane] = f1;
        float u0 = 0.f, u1 = 0.f, u2 = 0.f, u3 = 0.f;
        float v0 = 0.f, v1 = 0.f, v2 = 0.f, v3 = 0.f;
        #pragma unroll
        for (int d = 0; d < HD; d += 4) {
            const float4 A = *(const float4*)&fw[HD + d];      // broadcast b128
            const float4 Bv = *(const float4*)&fw[2 * HD + d];
            u0 = fmaf(A.x, wreg[d + 0], u0);
            u1 = fmaf(A.y, wreg[d + 1], u1);
            u2 = fmaf(A.z, wreg[d + 2], u2);
            u3 = fmaf(A.w, wreg[d + 3], u3);
            v0 = fmaf(Bv.x, wreg[d + 0], v0);
            v1 = fmaf(Bv.y, wreg[d + 1], v1);
            v2 = fmaf(Bv.z, wreg[d + 2], v2);
            v3 = fmaf(Bv.w, wreg[d + 3], v3);
        }
        float p = fmaxf((u0 + u1) + (u2 + u3) + bc1v, 0.f) * wc2v;
        float q = fmaxf((v0 + v1) + (v2 + v3) + bc1v, 0.f) * wc2v;
        wave_sum2(p, q);
        const float w0 = expf(p + bc2v);
        const float w1 = have1 ? expf(q + bc2v) : 0.f;
        zsum += w0 + w1;
        acc = fmaf(w0, f0, acc);
        acc = fmaf(w1, f1, acc);
    }
    const float y8 = acc / zsum;

    // ---- (3) pair edgeconv over {industry (slot0), y8} ----
    const float indv = fw[lane];                      // read back staged indv
    fw[HD + lane] = y8;
    float p0 = 0.f, p1 = 0.f, q0 = 0.f, q1 = 0.f;
    #pragma unroll
    for (int d = 0; d < HD; d += 4) {
        const float4 iv = *(const float4*)&fw[d];
        const float4 yv = *(const float4*)&fw[HD + d];
        p0 = fmaf(iv.x, wreg[d + 0], p0);
        p1 = fmaf(iv.y, wreg[d + 1], p1);
        p0 = fmaf(iv.z, wreg[d + 2], p0);
        p1 = fmaf(iv.w, wreg[d + 3], p1);
        q0 = fmaf(yv.x, wreg[d + 0], q0);
        q1 = fmaf(yv.y, wreg[d + 1], q1);
        q0 = fmaf(yv.z, wreg[d + 2], q0);
        q1 = fmaf(yv.w, wreg[d + 3], q1);
    }
    float zp = fmaxf(p0 + p1 + bc1v, 0.f) * wc2v;
    float zq = fmaxf(q0 + q1 + bc1v, 0.f) * wc2v;
    wave_sum2(zp, zq);
    const float w0 = expf(zp + bc2v), w1 = expf(zq + bc2v);
    out[(size_t)idx * HD + lane] = fmaf(w0, indv, w1 * y8) / (w0 + w1);
}

extern "C" void kernel_launch(void* const* d_in, const int* in_sizes, int n_in,
                              void* d_out, int out_size, void* d_ws, size_t ws_size,
                              hipStream_t stream) {
    const float* x     = (const float*)d_in[0];
    const int*   Hm    = (const int*)  d_in[1];
    const int*   adj   = (const int*)  d_in[2];
    // d_in[3] = nhid (unused scalar)
    const float* W     = (const float*)d_in[4];
    const float* a_hyp = (const float*)d_in[5];
    const float* a_ind = (const float*)d_in[6];
    const float* Wc1   = (const float*)d_in[7];
    const float* bc1   = (const float*)d_in[8];
    const float* wc2   = (const float*)d_in[9];
    const float* bc2   = (const float*)d_in[10];
    float* out = (float*)d_out;

    float* ws       = (float*)d_ws;
    float* h        = ws;                                 // T*N*HD
    float* s_hyp    = h + (size_t)T_DIM * N_DIM * HD;     // T*N
    float* s_ind    = s_hyp + T_DIM * N_DIM;              // T*N
    float* d_e      = s_ind + T_DIM * N_DIM;              // T*E
    int*   degs     = (int*)(d_e + T_DIM * E_DIM);        // N
    int*   nbrs     = degs + N_DIM;                       // N*NBR_CAP

    k1_h_s<<<K1_ROWBLK + K1_CSRBLK, 256, 0, stream>>>(
        x, W, a_hyp, a_ind, adj, h, s_hyp, s_ind, degs, nbrs);
    k2_de<<<T_DIM, 256, 0, stream>>>(Hm, s_hyp, d_e);
    k3_fused<<<T_DIM * N_DIM / 4, 256, 0, stream>>>(
        Hm, degs, nbrs, s_hyp, s_ind, d_e, h, Wc1, bc1, wc2, bc2, out);
}